// Round 20
// baseline (511.554 us; speedup 1.0000x reference)
//
#include <hip/hip_runtime.h>
#include <math.h>

typedef __attribute__((ext_vector_type(4))) float f32x4;
typedef __attribute__((ext_vector_type(2))) float f32x2;
typedef __attribute__((ext_vector_type(8))) short bf16x8;

__device__ __forceinline__ float b2f(unsigned short u) {
  return __uint_as_float(((unsigned)u) << 16);
}
__device__ __forceinline__ unsigned short f2b(float f) {
  unsigned x = __float_as_uint(f);
  unsigned r = (x + 0x7FFFu + ((x >> 16) & 1u)) >> 16;
  return (unsigned short)r;
}
__device__ __forceinline__ f32x2 bf2x2(unsigned u) {
  f32x2 r;
  r.x = __uint_as_float(u << 16);
  r.y = __uint_as_float(u & 0xFFFF0000u);
  return r;
}
__device__ __forceinline__ f32x2 pk_max(f32x2 a, f32x2 b) {
#if __has_builtin(__builtin_elementwise_max)
  return __builtin_elementwise_max(a, b);
#else
  f32x2 r; r.x = fmaxf(a.x, b.x); r.y = fmaxf(a.y, b.y); return r;
#endif
}
__device__ __forceinline__ f32x2 pk_fma(f32x2 a, f32x2 b, f32x2 c) {
#if __has_builtin(__builtin_elementwise_fma)
  return __builtin_elementwise_fma(a, b, c);
#else
  f32x2 r; r.x = fmaf(a.x, b.x, c.x); r.y = fmaf(a.y, b.y, c.y); return r;
#endif
}

// ---- fp8 e4m3 (OCP): HW cvt on gfx950 (hi-select immediate -> template) ---
#if __has_builtin(__builtin_amdgcn_cvt_pk_f32_fp8)
template<bool HI>
__device__ __forceinline__ f32x2 fp8x2_dec(unsigned w) {
  return __builtin_amdgcn_cvt_pk_f32_fp8(w, HI);
}
#else
__device__ __forceinline__ float fp8_dec1(unsigned b) {
  unsigned s = b >> 7, e = (b >> 3) & 15, m = b & 7;
  float v = (e == 0) ? (float)m * 0.001953125f
                     : __uint_as_float(((e - 7 + 127) << 23) | (m << 20));
  return s ? -v : v;
}
template<bool HI>
__device__ __forceinline__ f32x2 fp8x2_dec(unsigned w) {
  unsigned h = HI ? (w >> 16) : w;
  f32x2 r; r.x = fp8_dec1(h & 0xFF); r.y = fp8_dec1((h >> 8) & 0xFF);
  return r;
}
#endif
#if __has_builtin(__builtin_amdgcn_cvt_pk_fp8_f32)
__device__ __forceinline__ unsigned char fp8_enc_byte(float a) {
  return (unsigned char)(__builtin_amdgcn_cvt_pk_fp8_f32(a, a, 0, false) & 0xFF);
}
#else
__device__ __forceinline__ unsigned fp8_enc1(float f) {
  unsigned s = (__float_as_uint(f) >> 31) << 7;
  float a = fabsf(f);
  if (a >= 448.f) return s | 0x7E;
  if (a < 0.015625f) {
    int m = (int)(a * 512.f + 0.5f);
    return s | (unsigned)(m > 7 ? 7 : m);
  }
  int ex; (void)frexpf(a, &ex);
  int E = ex - 1;
  float sig = a * exp2f((float)(-E));
  int m = (int)((sig - 1.f) * 8.f + 0.5f);
  if (m == 8) { m = 0; E += 1; }
  if (E > 8) return s | 0x7E;
  return s | (unsigned)((E + 7) << 3) | (unsigned)m;
}
__device__ __forceinline__ unsigned char fp8_enc_byte(float a) {
  return (unsigned char)fp8_enc1(a);
}
#endif

// ---------------------------------------------------------------------------
// prep_all (segmented): [0,2048) weight transpose+cast; [2048,2048+CA) emb
// casts; last block masked bias sums.
// ---------------------------------------------------------------------------
__global__ __launch_bounds__(256) void prep_all(
    const float* __restrict__ Wl, const float* __restrict__ Wr,
    unsigned short* __restrict__ wt,
    const float* __restrict__ e0, const float* __restrict__ e1,
    const float* __restrict__ e2, unsigned short* __restrict__ x0,
    unsigned short* __restrict__ x1, unsigned short* __restrict__ x2,
    int n0, int n1, int n2,
    const float* __restrict__ bias, float* __restrict__ bsum, int CA)
{
  int blk = blockIdx.x;
  if (blk < 2048) {
    int elem = blk * 256 + threadIdx.x;
    int mat = elem >> 14;
    int c = (elem >> 7) & 127;
    int k = elem & 127;
    const float* srcb = (mat & 1) ? Wr : Wl;
    wt[elem] = f2b(srcb[((long)(mat >> 1) << 14) + (k << 7) + c]);
    return;
  }
  if (blk < 2048 + CA) {
    int i = (blk - 2048) * 256 + threadIdx.x;
    const float* s; unsigned short* d; int loc = i;
    if (loc < n0) { s = e0; d = x0; }
    else {
      loc -= n0;
      if (loc < n1) { s = e1; d = x1; }
      else { loc -= n1; if (loc >= n2) return; s = e2; d = x2; }
    }
    float4 v = *(const float4*)(s + (long)loc * 4);
    ushort4 o = {f2b(v.x), f2b(v.y), f2b(v.z), f2b(v.w)};
    *(ushort4*)(d + (long)loc * 4) = o;
    return;
  }
  // bias sums
  if (threadIdx.x >= 128) return;
  int c = threadIdx.x;
  const int TM[3] = {0x35, 0x42, 0x88};
  for (int l = 0; l < 2; ++l)
    for (int ty = 0; ty < 3; ++ty) {
      float s = 0.f;
      for (int t = 0; t < 8; ++t)
        if (TM[ty] & (1 << t)) s += bias[(l * 8 + t) * 128 + c];
      bsum[(l * 3 + ty) * 128 + c] = s;
    }
}

// ---------------------------------------------------------------------------
// Multi-weight MFMA projection: block stages one 128-row x-tile ONCE, then
// loops over up to 4 weight matrices. mode: 0 f32, 2 bf16, 3 fp8.
// Full-tile blocks take guard-free staging/epilogue paths.
// ---------------------------------------------------------------------------
struct MPJob {
  const unsigned short* x; int N; int nw;
  const unsigned short* wt[4]; void* out[4]; int mode[4];
};
struct MPArgs { MPJob j[4]; int off[5]; };

__global__ __launch_bounds__(256) void mproj_multi(MPArgs a)
{
  __shared__ __align__(16) char lx[32768];
  __shared__ __align__(16) char lw[32768];
  int blk = blockIdx.x, t = 0;
  while (blk >= a.off[t + 1]) ++t;
  const MPJob& J = a.j[t];
  const long r0 = (long)(blk - a.off[t]) * 128;
  const int tid = threadIdx.x;
  const int N = J.N;
  const bool full = (r0 + 128 <= (long)N);

  if (full) {
#pragma unroll
    for (int i = 0; i < 8; ++i) {
      int ch = i * 256 + tid;
      int row = ch >> 4, k0 = (ch & 15) << 3;
      uint4 xv = *(const uint4*)(J.x + (r0 + row) * 128 + k0);
      *(uint4*)(lx + ((row * 256 + k0 * 2) ^ ((row & 7) << 4))) = xv;
    }
  } else {
#pragma unroll
    for (int i = 0; i < 8; ++i) {
      int ch = i * 256 + tid;
      int row = ch >> 4, k0 = (ch & 15) << 3;
      uint4 xv = {0u, 0u, 0u, 0u};
      if (r0 + row < N) xv = *(const uint4*)(J.x + (r0 + row) * 128 + k0);
      *(uint4*)(lx + ((row * 256 + k0 * 2) ^ ((row & 7) << 4))) = xv;
    }
  }

  const int lane = tid & 63;
  const int lr = lane & 15, lk = lane >> 4;
  const int rbase = (tid >> 6) * 32;

  for (int w = 0; w < J.nw; ++w) {
    __syncthreads();
    const unsigned short* wt = J.wt[w];
#pragma unroll
    for (int i = 0; i < 8; ++i) {
      int ch = i * 256 + tid;
      int row = ch >> 4;
      uint4 wv = *(const uint4*)(wt + (long)ch * 8);
      *(uint4*)(lw + ((ch * 16) ^ ((row & 7) << 4))) = wv;
    }
    __syncthreads();

    f32x4 acc[2][8] = {};
#pragma unroll
    for (int kb = 0; kb < 4; ++kb) {
      int k = kb * 32 + lk * 8;
      int ra = rbase + lr;
      bf16x8 a0 = *(const bf16x8*)(lx + ((ra * 256 + k * 2) ^ ((ra & 7) << 4)));
      int rb = rbase + 16 + lr;
      bf16x8 a1 = *(const bf16x8*)(lx + ((rb * 256 + k * 2) ^ ((rb & 7) << 4)));
#pragma unroll
      for (int cc = 0; cc < 8; ++cc) {
        int col = cc * 16 + lr;
        bf16x8 bfr = *(const bf16x8*)(lw + ((col * 256 + k * 2) ^ ((col & 7) << 4)));
        acc[0][cc] = __builtin_amdgcn_mfma_f32_16x16x32_bf16(a0, bfr, acc[0][cc], 0, 0, 0);
        acc[1][cc] = __builtin_amdgcn_mfma_f32_16x16x32_bf16(a1, bfr, acc[1][cc], 0, 0, 0);
      }
    }
    int mode = J.mode[w];
    void* outv = J.out[w];
    if (full) {
#pragma unroll
      for (int rt = 0; rt < 2; ++rt) {
        int rowb = rbase + rt * 16 + lk * 4;
#pragma unroll
        for (int cc = 0; cc < 8; ++cc) {
          int col = cc * 16 + lr;
#pragma unroll
          for (int q = 0; q < 4; ++q) {
            long row = r0 + rowb + q;
            if (mode == 3)
              ((unsigned char*)outv)[row * 128 + col] = fp8_enc_byte(acc[rt][cc][q]);
            else if (mode == 2)
              ((unsigned short*)outv)[row * 128 + col] = f2b(acc[rt][cc][q]);
            else
              ((float*)outv)[row * 128 + col] = acc[rt][cc][q];
          }
        }
      }
    } else {
#pragma unroll
      for (int rt = 0; rt < 2; ++rt) {
        int rowb = rbase + rt * 16 + lk * 4;
#pragma unroll
        for (int cc = 0; cc < 8; ++cc) {
          int col = cc * 16 + lr;
#pragma unroll
          for (int q = 0; q < 4; ++q) {
            long row = r0 + rowb + q;
            if (row < N) {
              if (mode == 3)
                ((unsigned char*)outv)[row * 128 + col] = fp8_enc_byte(acc[rt][cc][q]);
              else if (mode == 2)
                ((unsigned short*)outv)[row * 128 + col] = f2b(acc[rt][cc][q]);
              else
                ((float*)outv)[row * 128 + col] = acc[rt][cc][q];
            }
          }
        }
      }
    }
  }
}

// ---------------------------------------------------------------------------
// Atomic-free bucketed CSR build (bucket = 128 dst nodes, 4096 edges/block).
// ---------------------------------------------------------------------------
struct BArgs {
  const int* src[5]; const int* dst[5];
  int* cnt[5];
  int* tmp[5];
  int* rs[5];
  int* csrc[5];
  int E[5], Nd[5], NB[5], B[5];
  int cOff[6], fOff[6];
};

__global__ __launch_bounds__(256) void bucket_count(BArgs a)
{
  __shared__ int h[512];
  int blk = blockIdx.x, t = 0;
  while (blk >= a.cOff[t + 1]) ++t;
  int lb = blk - a.cOff[t];
  int B = a.B[t], NB = a.NB[t], E = a.E[t];
  for (int i = threadIdx.x; i < B; i += 256) h[i] = 0;
  __syncthreads();
  const int* dst = a.dst[t];
  int base = lb * 4096;
#pragma unroll
  for (int j = 0; j < 16; ++j) {
    int e = base + j * 256 + threadIdx.x;
    if (e < E) atomicAdd(&h[dst[e] >> 7], 1);   // LDS atomic
  }
  __syncthreads();
  int* cnt = a.cnt[t];
  for (int b = threadIdx.x; b < B; b += 256) cnt[b * NB + lb] = h[b];
}

__global__ __launch_bounds__(1024) void bucket_scan(BArgs a)
{
  int t = blockIdx.x;
  int n = a.B[t] * a.NB[t];
  int* dp = a.cnt[t];
  __shared__ int wsum[16];
  __shared__ int sbase, ctot;
  int tid = threadIdx.x;
  int lane = tid & 63, wid = tid >> 6;
  if (tid == 0) sbase = 0;
  __syncthreads();
  for (int chunk = 0; chunk < n; chunk += 16384) {
    int idx0 = chunk + tid * 16;
    int v[16], lsum = 0;
#pragma unroll
    for (int j = 0; j < 16; ++j) {
      v[j] = (idx0 + j < n) ? dp[idx0 + j] : 0;
      lsum += v[j];
    }
    int sc = lsum;
#pragma unroll
    for (int o = 1; o < 64; o <<= 1) {
      int u = __shfl_up(sc, o);
      if (lane >= o) sc += u;
    }
    if (lane == 63) wsum[wid] = sc;
    __syncthreads();
    if (wid == 0) {
      int w = (lane < 16) ? wsum[lane] : 0;
      int s2 = w;
#pragma unroll
      for (int o = 1; o < 16; o <<= 1) {
        int u = __shfl_up(s2, o);
        if (lane >= o) s2 += u;
      }
      if (lane < 16) wsum[lane] = s2 - w;
      if (lane == 15) ctot = s2;
    }
    __syncthreads();
    int excl = sbase + wsum[wid] + (sc - lsum);
#pragma unroll
    for (int j = 0; j < 16; ++j) {
      if (idx0 + j < n) dp[idx0 + j] = excl;
      excl += v[j];
    }
    __syncthreads();
    if (tid == 0) sbase += ctot;
    __syncthreads();
  }
}

__global__ __launch_bounds__(256) void bucket_scatter(BArgs a)
{
  __shared__ int cur[512];
  int blk = blockIdx.x, t = 0;
  while (blk >= a.cOff[t + 1]) ++t;
  int lb = blk - a.cOff[t];
  int B = a.B[t], NB = a.NB[t], E = a.E[t];
  const int* cnt = a.cnt[t];
  for (int b = threadIdx.x; b < B; b += 256) cur[b] = cnt[b * NB + lb];
  __syncthreads();
  const int* src = a.src[t];
  const int* dst = a.dst[t];
  int* tmp = a.tmp[t];
  int base = lb * 4096;
#pragma unroll
  for (int j = 0; j < 16; ++j) {
    int e = base + j * 256 + threadIdx.x;
    if (e < E) {
      int dv = dst[e];
      int pos = atomicAdd(&cur[dv >> 7], 1);    // LDS atomic
      tmp[pos] = ((dv & 127) << 16) | src[e];
    }
  }
}

__global__ __launch_bounds__(256) void bucket_finalize(BArgs a)
{
  __shared__ int h[128], sc[128], ex[128], cur[128];
  int blk = blockIdx.x, t = 0;
  while (blk >= a.fOff[t + 1]) ++t;
  int b = blk - a.fOff[t];
  int B = a.B[t], NB = a.NB[t], E = a.E[t], Nd = a.Nd[t];
  const int* cnt = a.cnt[t];
  const int* tmp = a.tmp[t];
  int* rs = a.rs[t];
  int* csrc = a.csrc[t];
  int tid = threadIdx.x;
  int beg = cnt[b * NB];
  int end = (b + 1 < B) ? cnt[(b + 1) * NB] : E;
  if (tid < 128) h[tid] = 0;
  __syncthreads();
  for (int i = beg + tid; i < end; i += 256)
    atomicAdd(&h[tmp[i] >> 16], 1);             // LDS atomic
  __syncthreads();
  if (tid < 128) sc[tid] = h[tid];
  __syncthreads();
#pragma unroll
  for (int off = 1; off < 128; off <<= 1) {
    int v = (tid < 128 && tid >= off) ? sc[tid - off] : 0;
    __syncthreads();
    if (tid < 128) sc[tid] += v;
    __syncthreads();
  }
  if (tid < 128) {
    ex[tid] = sc[tid] - h[tid];
    cur[tid] = 0;
    int dg = b * 128 + tid;
    if (dg < Nd) rs[dg] = beg + ex[tid];
  }
  if (b == B - 1 && tid == 0) rs[Nd] = E;
  __syncthreads();
  for (int i = beg + tid; i < end; i += 256) {
    int v = tmp[i];
    int d = v >> 16;
    int r = atomicAdd(&cur[d], 1);              // LDS atomic
    csrc[beg + ex[d] + r] = v & 0xFFFF;
  }
}

// ---------------------------------------------------------------------------
// Fused gather + LayerNorm. Two shapes (identical to r19 passing build):
//  fast==0 (gene/mirna): 1 row/wave, 16 lanes/edge, 4 quarter-streams.
//  fast==1 (cpg, low degree): 4 rows/wave, serial edges, no butterfly.
// ---------------------------------------------------------------------------
struct GSeg {
  const int* rs[3]; const int* csrc[3];
  const unsigned char* hs[3]; const unsigned short* hd[3];
  const float* att[3];
  const float* aggSelf;
  const float* xin;
  float* xf; unsigned short* xb;
  const float* bsum;
  const float* gam; const float* bet;
  int Nd; int ntypes; int fast;
};
struct GArgs { GSeg s[3]; int off[4]; };

#define GA_EDGE(U)                                                          \
    {                                                                       \
      f32x2 h0 = fp8x2_dec<false>((U).x), h1 = fp8x2_dec<true>((U).x);      \
      f32x2 h2 = fp8x2_dec<false>((U).y), h3 = fp8x2_dec<true>((U).y);      \
      f32x2 v0 = h0 + H0, v1 = h1 + H1, v2 = h2 + H2, v3 = h3 + H3;         \
      v0 = pk_max(v0, v0 * 0.2f);                                           \
      v1 = pk_max(v1, v1 * 0.2f);                                           \
      v2 = pk_max(v2, v2 * 0.2f);                                           \
      v3 = pk_max(v3, v3 * 0.2f);                                           \
      f32x2 pv = pk_fma(v0, A0, pk_fma(v1, A1, pk_fma(v2, A2, v3 * A3)));   \
      float p = pv.x + pv.y;                                                \
      p += __shfl_xor(p, 1);                                                \
      float a = __expf(fminf(p, 60.f));                                     \
      f32x2 av = {a, a};                                                    \
      n0 = pk_fma(h0, av, n0);                                              \
      n1 = pk_fma(h1, av, n1);                                              \
      n2 = pk_fma(h2, av, n2);                                              \
      n3 = pk_fma(h3, av, n3);                                              \
      D += a;                                                               \
    }

__global__ __launch_bounds__(256) void gat_gather_ln(GArgs g)
{
  int blk = blockIdx.x, si = 0;
  while (blk >= g.off[si + 1]) ++si;
  const GSeg& sg = g.s[si];
  int lane = threadIdx.x & 63;

  if (sg.fast) {
    int wv = threadIdx.x >> 6;
    int grp = lane >> 4, j = lane & 15;
    int d = (blk - g.off[si]) * 16 + wv * 4 + grp;
    bool act = d < sg.Nd;
    const float* ap = sg.att[0] + 8 * j;
    float4 aa = *(const float4*)ap;
    float4 ab = *(const float4*)(ap + 4);
    f32x2 A0 = {aa.x, aa.y}, A1 = {aa.z, aa.w};
    f32x2 A2 = {ab.x, ab.y}, A3 = {ab.z, ab.w};
    f32x2 H0 = {0.f, 0.f}, H1 = {0.f, 0.f}, H2 = {0.f, 0.f}, H3 = {0.f, 0.f};
    int beg = 0, end = 0;
    if (act) {
      uint4 hu = *((const uint4*)(sg.hd[0] + (long)d * 128) + j);
      H0 = bf2x2(hu.x); H1 = bf2x2(hu.y);
      H2 = bf2x2(hu.z); H3 = bf2x2(hu.w);
      beg = sg.rs[0][d];
      end = sg.rs[0][d + 1];
    }
    const int* cs = sg.csrc[0];
    const unsigned char* hsk = sg.hs[0];
    f32x2 n0 = {0.f, 0.f}, n1 = {0.f, 0.f}, n2 = {0.f, 0.f}, n3 = {0.f, 0.f};
    float D = 0.f;
    int i = beg;
    int sA = (i < end) ? cs[i] : 0;
    int sB = (i + 1 < end) ? cs[i + 1] : 0;
    for (; i + 1 < end; i += 2) {
      uint2 u0 = *((const uint2*)(hsk + (long)sA * 128) + j);
      uint2 u1 = *((const uint2*)(hsk + (long)sB * 128) + j);
      sA = (i + 2 < end) ? cs[i + 2] : 0;
      sB = (i + 3 < end) ? cs[i + 3] : 0;
      GA_EDGE(u0);
      GA_EDGE(u1);
    }
    if (i < end) {
      uint2 u = *((const uint2*)(hsk + (long)sA * 128) + j);
      GA_EDGE(u);
    }
    float inv = 1.f / (D + 1e-16f);
    f32x2 iv = {inv, inv};
    f32x2 T0 = n0 * iv, T1 = n1 * iv, T2 = n2 * iv, T3 = n3 * iv;

    long base = (long)d * 128 + 8 * j;
    float v[8] = {T0.x, T0.y, T1.x, T1.y, T2.x, T2.y, T3.x, T3.y};
    if (act) {
      float4 sA0 = *(const float4*)(sg.aggSelf + base);
      float4 sA1 = *(const float4*)(sg.aggSelf + base + 4);
      float4 bb0 = *(const float4*)(sg.bsum + 8 * j);
      float4 bb1 = *(const float4*)(sg.bsum + 8 * j + 4);
      v[0] += sA0.x + bb0.x; v[1] += sA0.y + bb0.y;
      v[2] += sA0.z + bb0.z; v[3] += sA0.w + bb0.w;
      v[4] += sA1.x + bb1.x; v[5] += sA1.y + bb1.y;
      v[6] += sA1.z + bb1.z; v[7] += sA1.w + bb1.w;
    }
#pragma unroll
    for (int c = 0; c < 8; ++c) v[c] = v[c] > 0.f ? v[c] : __expf(v[c]) - 1.f;
    float xr[8] = {v[0], v[1], v[2], v[3], v[4], v[5], v[6], v[7]};
    if (act) {
      float4 xi0 = *(const float4*)(sg.xin + base);
      float4 xi1 = *(const float4*)(sg.xin + base + 4);
      xr[0] += xi0.x; xr[1] += xi0.y; xr[2] += xi0.z; xr[3] += xi0.w;
      xr[4] += xi1.x; xr[5] += xi1.y; xr[6] += xi1.z; xr[7] += xi1.w;
    }
    float ssum = ((xr[0] + xr[1]) + (xr[2] + xr[3])) +
                 ((xr[4] + xr[5]) + (xr[6] + xr[7]));
#pragma unroll
    for (int o = 1; o < 16; o <<= 1) ssum += __shfl_xor(ssum, o);
    float mu = ssum * 0.0078125f;
    float qs = 0.f;
#pragma unroll
    for (int c = 0; c < 8; ++c) { float dd = xr[c] - mu; qs += dd * dd; }
#pragma unroll
    for (int o = 1; o < 16; o <<= 1) qs += __shfl_xor(qs, o);
    float rr = rsqrtf(qs * 0.0078125f + 1e-5f);
    if (act) {
      float4 g0 = *(const float4*)(sg.gam + 8 * j);
      float4 g1 = *(const float4*)(sg.gam + 8 * j + 4);
      float4 e0 = *(const float4*)(sg.bet + 8 * j);
      float4 e1 = *(const float4*)(sg.bet + 8 * j + 4);
      float y[8];
      y[0] = (xr[0] - mu) * rr * g0.x + e0.x;
      y[1] = (xr[1] - mu) * rr * g0.y + e0.y;
      y[2] = (xr[2] - mu) * rr * g0.z + e0.z;
      y[3] = (xr[3] - mu) * rr * g0.w + e0.w;
      y[4] = (xr[4] - mu) * rr * g1.x + e1.x;
      y[5] = (xr[5] - mu) * rr * g1.y + e1.y;
      y[6] = (xr[6] - mu) * rr * g1.z + e1.z;
      y[7] = (xr[7] - mu) * rr * g1.w + e1.w;
      float4 o0 = {y[0], y[1], y[2], y[3]};
      float4 o1 = {y[4], y[5], y[6], y[7]};
      *(float4*)(sg.xf + base) = o0;
      *(float4*)(sg.xf + base + 4) = o1;
      uint4 ub;
      ub.x = (unsigned)f2b(y[0]) | ((unsigned)f2b(y[1]) << 16);
      ub.y = (unsigned)f2b(y[2]) | ((unsigned)f2b(y[3]) << 16);
      ub.z = (unsigned)f2b(y[4]) | ((unsigned)f2b(y[5]) << 16);
      ub.w = (unsigned)f2b(y[6]) | ((unsigned)f2b(y[7]) << 16);
      *(uint4*)(sg.xb + base) = ub;
    }
    return;
  }

  // ---- standard path: 1 row/wave, 4 quarter-streams ----
  int d = (blk - g.off[si]) * 4 + (threadIdx.x >> 6);
  if (d >= sg.Nd) return;
  int q = lane >> 4, j = lane & 15;
  f32x2 T0 = {0.f, 0.f}, T1 = {0.f, 0.f}, T2 = {0.f, 0.f}, T3 = {0.f, 0.f};
  for (int k = 0; k < sg.ntypes; ++k) {
    const float* ap = sg.att[k] + 8 * j;
    float4 aa = *(const float4*)ap;
    float4 ab = *(const float4*)(ap + 4);
    f32x2 A0 = {aa.x, aa.y}, A1 = {aa.z, aa.w};
    f32x2 A2 = {ab.x, ab.y}, A3 = {ab.z, ab.w};
    uint4 hu = *((const uint4*)(sg.hd[k] + (long)d * 128) + j);
    f32x2 H0 = bf2x2(hu.x), H1 = bf2x2(hu.y);
    f32x2 H2 = bf2x2(hu.z), H3 = bf2x2(hu.w);
    const int* cs = sg.csrc[k];
    const unsigned char* hsk = sg.hs[k];
    int beg = sg.rs[k][d], end = sg.rs[k][d + 1];
    f32x2 n0 = {0.f, 0.f}, n1 = {0.f, 0.f}, n2 = {0.f, 0.f}, n3 = {0.f, 0.f};
    float D = 0.f;
    int i = beg + q;
    int sA = (i < end) ? cs[i] : 0;
    int sB = (i + 4 < end) ? cs[i + 4] : 0;
    for (; i + 4 < end; i += 8) {
      uint2 u0 = *((const uint2*)(hsk + (long)sA * 128) + j);
      uint2 u1 = *((const uint2*)(hsk + (long)sB * 128) + j);
      sA = (i + 8 < end) ? cs[i + 8] : 0;
      sB = (i + 12 < end) ? cs[i + 12] : 0;
      GA_EDGE(u0);
      GA_EDGE(u1);
    }
    if (i < end) {
      uint2 u = *((const uint2*)(hsk + (long)sA * 128) + j);
      GA_EDGE(u);
    }
#pragma unroll
    for (int o = 16; o < 64; o <<= 1) {
      n0.x += __shfl_xor(n0.x, o); n0.y += __shfl_xor(n0.y, o);
      n1.x += __shfl_xor(n1.x, o); n1.y += __shfl_xor(n1.y, o);
      n2.x += __shfl_xor(n2.x, o); n2.y += __shfl_xor(n2.y, o);
      n3.x += __shfl_xor(n3.x, o); n3.y += __shfl_xor(n3.y, o);
      D += __shfl_xor(D, o);
    }
    float inv = 1.f / (D + 1e-16f);
    f32x2 iv = {inv, inv};
    T0 = pk_fma(n0, iv, T0);
    T1 = pk_fma(n1, iv, T1);
    T2 = pk_fma(n2, iv, T2);
    T3 = pk_fma(n3, iv, T3);
  }

  long base = (long)d * 128 + 8 * j;
  float4 sA0 = *(const float4*)(sg.aggSelf + base);
  float4 sA1 = *(const float4*)(sg.aggSelf + base + 4);
  float4 bb0 = *(const float4*)(sg.bsum + 8 * j);
  float4 bb1 = *(const float4*)(sg.bsum + 8 * j + 4);
  float v[8];
  v[0] = sA0.x + T0.x + bb0.x; v[1] = sA0.y + T0.y + bb0.y;
  v[2] = sA0.z + T1.x + bb0.z; v[3] = sA0.w + T1.y + bb0.w;
  v[4] = sA1.x + T2.x + bb1.x; v[5] = sA1.y + T2.y + bb1.y;
  v[6] = sA1.z + T3.x + bb1.z; v[7] = sA1.w + T3.y + bb1.w;
#pragma unroll
  for (int c = 0; c < 8; ++c) v[c] = v[c] > 0.f ? v[c] : __expf(v[c]) - 1.f;
  float4 xi0 = *(const float4*)(sg.xin + base);
  float4 xi1 = *(const float4*)(sg.xin + base + 4);
  float xr[8] = {xi0.x + v[0], xi0.y + v[1], xi0.z + v[2], xi0.w + v[3],
                 xi1.x + v[4], xi1.y + v[5], xi1.z + v[6], xi1.w + v[7]};
  float ssum = ((xr[0] + xr[1]) + (xr[2] + xr[3])) +
               ((xr[4] + xr[5]) + (xr[6] + xr[7]));
#pragma unroll
  for (int o = 1; o < 16; o <<= 1) ssum += __shfl_xor(ssum, o);
  float mu = ssum * 0.0078125f;
  float qs = 0.f;
#pragma unroll
  for (int c = 0; c < 8; ++c) { float dd = xr[c] - mu; qs += dd * dd; }
#pragma unroll
  for (int o = 1; o < 16; o <<= 1) qs += __shfl_xor(qs, o);
  float rr = rsqrtf(qs * 0.0078125f + 1e-5f);
  float4 g0 = *(const float4*)(sg.gam + 8 * j);
  float4 g1 = *(const float4*)(sg.gam + 8 * j + 4);
  float4 e0 = *(const float4*)(sg.bet + 8 * j);
  float4 e1 = *(const float4*)(sg.bet + 8 * j + 4);
  float y[8];
  y[0] = (xr[0] - mu) * rr * g0.x + e0.x;
  y[1] = (xr[1] - mu) * rr * g0.y + e0.y;
  y[2] = (xr[2] - mu) * rr * g0.z + e0.z;
  y[3] = (xr[3] - mu) * rr * g0.w + e0.w;
  y[4] = (xr[4] - mu) * rr * g1.x + e1.x;
  y[5] = (xr[5] - mu) * rr * g1.y + e1.y;
  y[6] = (xr[6] - mu) * rr * g1.z + e1.z;
  y[7] = (xr[7] - mu) * rr * g1.w + e1.w;
  if (q == 0) {
    float4 o0 = {y[0], y[1], y[2], y[3]};
    float4 o1 = {y[4], y[5], y[6], y[7]};
    *(float4*)(sg.xf + base) = o0;
    *(float4*)(sg.xf + base + 4) = o1;
    uint4 ub;
    ub.x = (unsigned)f2b(y[0]) | ((unsigned)f2b(y[1]) << 16);
    ub.y = (unsigned)f2b(y[2]) | ((unsigned)f2b(y[3]) << 16);
    ub.z = (unsigned)f2b(y[4]) | ((unsigned)f2b(y[5]) << 16);
    ub.w = (unsigned)f2b(y[6]) | ((unsigned)f2b(y[7]) << 16);
    *(uint4*)(sg.xb + base) = ub;
  }
}
#undef GA_EDGE

// ---------------------------------------------------------------------------
// zgemm stage 1: TWO 64-row chunks per block (halves partial traffic).
// ---------------------------------------------------------------------------
struct ZArgs {
  const float* batch[3]; const float* x[3]; float* zp[3]; int N[3];
  int off[4];
};

__global__ __launch_bounds__(256) void zgemm_all(ZArgs z)
{
  __shared__ __align__(16) float xl[64 * 128];
  __shared__ __align__(16) float bl[64 * 65];
  int blk = blockIdx.x, s = 0;
  while (blk >= z.off[s + 1]) ++s;
  int c = blk - z.off[s];
  const float* batch = z.batch[s];
  const float* x = z.x[s];
  int N = z.N[s];
  int tid = threadIdx.x;
  int cg = (tid & 31) * 4;
  int bg = (tid >> 5) * 8;
  float acc[8][4] = {};
#pragma unroll
  for (int cc = 0; cc < 2; ++cc) {
    int n0 = (c * 2 + cc) * 64;
    if (n0 >= N) break;
    __syncthreads();
    for (int i = tid; i < 64 * 128; i += 256) {
      int nn = i >> 7;
      xl[i] = (n0 + nn < N) ? x[(long)(n0 + nn) * 128 + (i & 127)] : 0.f;
    }
    for (int i = tid; i < 64 * 64; i += 256) {
      int b = i >> 6, nn = i & 63;
      bl[nn * 65 + b] = (n0 + nn < N) ? batch[(long)b * N + n0 + nn] : 0.f;
    }
    __syncthreads();
    for (int nn = 0; nn < 64; ++nn) {
      float4 xv = *(const float4*)(xl + nn * 128 + cg);
#pragma unroll
      for (int i = 0; i < 8; ++i) {
        float bv = bl[nn * 65 + bg + i];
        acc[i][0] = fmaf(bv, xv.x, acc[i][0]);
        acc[i][1] = fmaf(bv, xv.y, acc[i][1]);
        acc[i][2] = fmaf(bv, xv.z, acc[i][2]);
        acc[i][3] = fmaf(bv, xv.w, acc[i][3]);
      }
    }
  }
  float* zp = z.zp[s] + (long)c * 8192;
#pragma unroll
  for (int i = 0; i < 8; ++i) {
    float4 v = {acc[i][0], acc[i][1], acc[i][2], acc[i][3]};
    *(float4*)(zp + (bg + i) * 128 + cg) = v;
  }
}

// ---------------------------------------------------------------------------
// zfinal: partial reduce (8 dual accumulators) + scale + LayerNorm -> out.
// ---------------------------------------------------------------------------
__global__ __launch_bounds__(256) void zfinal(
    const float* __restrict__ zp0, const float* __restrict__ zp1,
    const float* __restrict__ zp2, int G0, int G1, int G2,
    float s0, float s1, float s2, const float* __restrict__ gam,
    const float* __restrict__ bet, float* __restrict__ out)
{
  int blk = blockIdx.x;
  int ty = blk >> 4;
  int rowL = (blk & 15) * 4 + (threadIdx.x >> 6);
  int lane = threadIdx.x & 63;
  const float* zp = ty == 0 ? zp0 : (ty == 1 ? zp1 : zp2);
  int G = ty == 0 ? G0 : (ty == 1 ? G1 : G2);
  float sc = ty == 0 ? s0 : (ty == 1 ? s1 : s2);
  long i0 = rowL * 128 + lane, i1 = i0 + 64;
  float a0[8], a1[8];
#pragma unroll
  for (int u = 0; u < 8; ++u) { a0[u] = 0.f; a1[u] = 0.f; }
  int g = 0;
  for (; g + 8 <= G; g += 8) {
#pragma unroll
    for (int u = 0; u < 8; ++u) {
      a0[u] += zp[(long)(g + u) * 8192 + i0];
      a1[u] += zp[(long)(g + u) * 8192 + i1];
    }
  }
  for (; g < G; ++g) { a0[0] += zp[(long)g * 8192 + i0]; a1[0] += zp[(long)g * 8192 + i1]; }
  float x0 = (((a0[0] + a0[1]) + (a0[2] + a0[3])) + ((a0[4] + a0[5]) + (a0[6] + a0[7]))) * sc;
  float x1 = (((a1[0] + a1[1]) + (a1[2] + a1[3])) + ((a1[4] + a1[5]) + (a1[6] + a1[7]))) * sc;
  float s = x0 + x1;
#pragma unroll
  for (int o = 32; o > 0; o >>= 1) s += __shfl_xor(s, o);
  float mu = s * 0.0078125f;
  float d0 = x0 - mu, d1 = x1 - mu;
  float qv = d0 * d0 + d1 * d1;
#pragma unroll
  for (int o = 32; o > 0; o >>= 1) qv += __shfl_xor(qv, o);
  float r = rsqrtf(qv * 0.0078125f + 1e-5f);
  long base = (long)(ty * 64 + rowL) * 128;
  out[base + lane]      = d0 * r * gam[ty * 128 + lane]      + bet[ty * 128 + lane];
  out[base + 64 + lane] = d1 * r * gam[ty * 128 + 64 + lane] + bet[ty * 128 + 64 + lane];
}

// ---------------------------------------------------------------------------
extern "C" void kernel_launch(void* const* d_in, const int* in_sizes, int n_in,
                              void* d_out, int out_size, void* d_ws, size_t ws_size,
                              hipStream_t stream)
{
  const float* batchp[3] = {(const float*)d_in[0], (const float*)d_in[1],
                            (const float*)d_in[2]};
  const float* emb[3] = {(const float*)d_in[3], (const float*)d_in[4],
                         (const float*)d_in[5]};
  const float* Wl   = (const float*)d_in[6];
  const float* Wr   = (const float*)d_in[7];
  const float* att  = (const float*)d_in[8];
  const float* bias = (const float*)d_in[9];
  const float* lng  = (const float*)d_in[10];
  const float* lnb  = (const float*)d_in[11];
  const float* outg = (const float*)d_in[12];
  const float* outb = (const float*)d_in[13];
  const int* eiP[8]; int E[8];
  for (int t = 0; t < 8; ++t) { eiP[t] = (const int*)d_in[14 + t]; E[t] = in_sizes[14 + t] / 2; }
  int Nn[3] = {in_sizes[3] / 128, in_sizes[4] / 128, in_sizes[5] / 128};
  long Ntot = (long)Nn[0] + Nn[1] + Nn[2];

  const int SI[5] = {1, 0, 2, 0, 0};
  const int DI[5] = {0, 1, 0, 2, 0};

  char* p = (char*)d_ws;
  auto carve = [&](size_t b) -> void* {
    void* r = (void*)p; p += (b + 255) & ~(size_t)255; return r;
  };
  float* xf[3];
  for (int ty = 0; ty < 3; ++ty) xf[ty] = (float*)carve((size_t)Nn[ty] * 128 * 4);
  unsigned short* xb[3];
  for (int ty = 0; ty < 3; ++ty) xb[ty] = (unsigned short*)carve((size_t)Nn[ty] * 128 * 2);
  float* aggAll = (float*)carve((size_t)Ntot * 128 * 4);
  float* agg[3] = {aggAll, aggAll + (long)Nn[0] * 128, aggAll + ((long)Nn[0] + Nn[1]) * 128};
  unsigned short* hdT[5];
  for (int t = 0; t < 5; ++t) hdT[t] = (unsigned short*)carve((size_t)Nn[DI[t]] * 128 * 2);
  long hsElems = 0;
  for (int t = 0; t < 5; ++t) hsElems += (long)Nn[SI[t]] * 128;
  unsigned char* hs8base = (unsigned char*)carve((size_t)hsElems);
  unsigned char* hs8T[5];
  {
    unsigned char* q8 = hs8base;
    for (int t = 0; t < 5; ++t) { hs8T[t] = q8; q8 += (long)Nn[SI[t]] * 128; }
  }
  float* bsumBuf = (float*)carve(2 * 3 * 128 * 4);
  unsigned short* wtb = (unsigned short*)carve((size_t)32 * 16384 * 2);

  int nch[3], nch2[3];
  for (int ty = 0; ty < 3; ++ty) {
    nch[ty] = (Nn[ty] + 63) / 64;
    nch2[ty] = (nch[ty] + 1) / 2;
  }
  float* zpBase = (float*)carve((size_t)(nch2[0] + nch2[1] + nch2[2]) * 8192 * 4);
  float* zp[3];
  zp[0] = zpBase;
  zp[1] = zp[0] + (long)nch2[0] * 8192;
  zp[2] = zp[1] + (long)nch2[1] * 8192;

  BArgs ba;
  {
    int cOff = 0, fOff = 0;
    for (int t = 0; t < 5; ++t) {
      int nd = Nn[DI[t]];
      ba.src[t] = eiP[t];
      ba.dst[t] = eiP[t] + E[t];
      ba.E[t] = E[t];
      ba.Nd[t] = nd;
      ba.NB[t] = (E[t] + 4095) / 4096;
      ba.B[t] = (nd + 127) / 128;
      ba.cnt[t] = (int*)carve((size_t)ba.B[t] * ba.NB[t] * 4);
      ba.tmp[t] = (int*)carve((size_t)E[t] * 4);
      ba.rs[t] = (int*)carve((size_t)(nd + 1) * 4);
      ba.csrc[t] = (int*)carve((size_t)E[t] * 4);
      ba.cOff[t] = cOff; cOff += ba.NB[t];
      ba.fOff[t] = fOff; fOff += ba.B[t];
    }
    ba.cOff[5] = cOff;
    ba.fOff[5] = fOff;
  }
  if ((size_t)(p - (char*)d_ws) > ws_size) return;

  auto WTB = [&](int l, int t, int which) {
    return wtb + ((long)((l * 8 + t) * 2 + which) << 14);
  };

  // 0) fused prep: weights + emb casts + bias sums (one launch)
  {
    int n0 = Nn[0] * 32, n1 = Nn[1] * 32, n2 = Nn[2] * 32;
    int CA = (n0 + n1 + n2 + 255) / 256;
    prep_all<<<2048 + CA + 1, 256, 0, stream>>>(
        Wl, Wr, wtb, emb[0], emb[1], emb[2], xb[0], xb[1], xb[2],
        n0, n1, n2, bias, bsumBuf, CA);
  }

  // 1) CSR build (4 launches, zero global atomics)
  bucket_count<<<ba.cOff[5], 256, 0, stream>>>(ba);
  bucket_scan<<<5, 1024, 0, stream>>>(ba);
  bucket_scatter<<<ba.cOff[5], 256, 0, stream>>>(ba);
  bucket_finalize<<<ba.fOff[5], 256, 0, stream>>>(ba);

  const int GT[3][3] = {{0, 2, 4}, {1, -1, -1}, {3, -1, -1}};
  const int GN[3] = {3, 1, 1};

  for (int l = 0; l < 2; ++l) {
    const float* xinf[3] = {l == 0 ? emb[0] : xf[0],
                            l == 0 ? emb[1] : xf[1],
                            l == 0 ? emb[2] : xf[2]};
    // A) all 13 projections, multi-weight fused
    MPArgs mp;
    {
      int off = 0, nj = 0;
      auto addJob = [&](const unsigned short* x, int N) {
        mp.j[nj].x = x; mp.j[nj].N = N; mp.j[nj].nw = 0;
        mp.off[nj] = off; off += (N + 127) / 128;
        return nj++;
      };
      auto addW = [&](int ji, const unsigned short* wt, void* out, int mode) {
        MPJob& J = mp.j[ji];
        J.wt[J.nw] = wt; J.out[J.nw] = out; J.mode[J.nw] = mode; J.nw++;
      };
      int ga_ = addJob(xb[0], Nn[0]);
      addW(ga_, WTB(l, 1, 0), hs8T[1], 3);
      addW(ga_, WTB(l, 3, 0), hs8T[3], 3);
      addW(ga_, WTB(l, 4, 0), hs8T[4], 3);
      addW(ga_, WTB(l, 0, 1), hdT[0], 2);
      int gb_ = addJob(xb[0], Nn[0]);
      addW(gb_, WTB(l, 2, 1), hdT[2], 2);
      addW(gb_, WTB(l, 4, 1), hdT[4], 2);
      addW(gb_, WTB(l, 5, 0), agg[0], 0);
      int cj_ = addJob(xb[1], Nn[1]);
      addW(cj_, WTB(l, 0, 0), hs8T[0], 3);
      addW(cj_, WTB(l, 1, 1), hdT[1], 2);
      addW(cj_, WTB(l, 6, 0), agg[1], 0);
      int mj_ = addJob(xb[2], Nn[2]);
      addW(mj_, WTB(l, 2, 0), hs8T[2], 3);
      addW(mj_, WTB(l, 3, 1), hdT[3], 2);
      addW(mj_, WTB(l, 7, 0), agg[2], 0);
      mp.off[4] = off;
      mproj_multi<<<off, 256, 0, stream>>>(mp);
    }
    // B) fused gather + LN (cpg uses fast 4-rows-per-wave path)
    GArgs ga;
    {
      int off = 0;
      for (int s = 0; s < 3; ++s) {
        GSeg& sg = ga.s[s];
        sg.aggSelf = agg[s];
        sg.xin = xinf[s];
        sg.xf = xf[s];
        sg.xb = xb[s];
        sg.bsum = bsumBuf + (long)(l * 3 + s) * 128;
        sg.gam = lng + (long)(l * 3 + s) * 128;
        sg.bet = lnb + (long)(l * 3 + s) * 128;
        sg.Nd = Nn[s];
        sg.ntypes = GN[s];
        sg.fast = (s == 1) ? 1 : 0;
        for (int k = 0; k < GN[s]; ++k) {
          int t = GT[s][k];
          sg.rs[k] = ba.rs[t];
          sg.csrc[k] = ba.csrc[t];
          sg.hs[k] = hs8T[t];
          sg.hd[k] = hdT[t];
          sg.att[k] = att + (long)(l * 8 + t) * 128;
        }
        ga.off[s] = off;
        off += sg.fast ? (Nn[s] + 15) / 16 : (Nn[s] + 3) / 4;
      }
      ga.off[3] = off;
      gat_gather_ln<<<off, 256, 0, stream>>>(ga);
    }
  }

  ZArgs za;
  {
    int off = 0;
    for (int ty = 0; ty < 3; ++ty) {
      za.batch[ty] = batchp[ty];
      za.x[ty] = xf[ty];
      za.zp[ty] = zp[ty];
      za.N[ty] = Nn[ty];
      za.off[ty] = off;
      off += nch2[ty];
    }
    za.off[3] = off;
    zgemm_all<<<off, 256, 0, stream>>>(za);
  }
  zfinal<<<48, 256, 0, stream>>>(
      zp[0], zp[1], zp[2], nch2[0], nch2[1], nch2[2],
      (float)(1.0 / sqrt((double)Nn[0])), (float)(1.0 / sqrt((double)Nn[1])),
      (float)(1.0 / sqrt((double)Nn[2])), outg, outb, (float*)d_out);
}

// Round 21
// 471.509 us; speedup vs baseline: 1.0849x; 1.0849x over previous
//
#include <hip/hip_runtime.h>
#include <math.h>

typedef __attribute__((ext_vector_type(4))) float f32x4;
typedef __attribute__((ext_vector_type(2))) float f32x2;
typedef __attribute__((ext_vector_type(8))) short bf16x8;

__device__ __forceinline__ float b2f(unsigned short u) {
  return __uint_as_float(((unsigned)u) << 16);
}
__device__ __forceinline__ unsigned short f2b(float f) {
  unsigned x = __float_as_uint(f);
  unsigned r = (x + 0x7FFFu + ((x >> 16) & 1u)) >> 16;
  return (unsigned short)r;
}
__device__ __forceinline__ f32x2 bf2x2(unsigned u) {
  f32x2 r;
  r.x = __uint_as_float(u << 16);
  r.y = __uint_as_float(u & 0xFFFF0000u);
  return r;
}
__device__ __forceinline__ f32x2 pk_max(f32x2 a, f32x2 b) {
#if __has_builtin(__builtin_elementwise_max)
  return __builtin_elementwise_max(a, b);
#else
  f32x2 r; r.x = fmaxf(a.x, b.x); r.y = fmaxf(a.y, b.y); return r;
#endif
}
__device__ __forceinline__ f32x2 pk_fma(f32x2 a, f32x2 b, f32x2 c) {
#if __has_builtin(__builtin_elementwise_fma)
  return __builtin_elementwise_fma(a, b, c);
#else
  f32x2 r; r.x = fmaf(a.x, b.x, c.x); r.y = fmaf(a.y, b.y, c.y); return r;
#endif
}

// ---- fp8 e4m3 (OCP): HW cvt on gfx950 (hi-select immediate -> template) ---
#if __has_builtin(__builtin_amdgcn_cvt_pk_f32_fp8)
template<bool HI>
__device__ __forceinline__ f32x2 fp8x2_dec(unsigned w) {
  return __builtin_amdgcn_cvt_pk_f32_fp8(w, HI);
}
#else
__device__ __forceinline__ float fp8_dec1(unsigned b) {
  unsigned s = b >> 7, e = (b >> 3) & 15, m = b & 7;
  float v = (e == 0) ? (float)m * 0.001953125f
                     : __uint_as_float(((e - 7 + 127) << 23) | (m << 20));
  return s ? -v : v;
}
template<bool HI>
__device__ __forceinline__ f32x2 fp8x2_dec(unsigned w) {
  unsigned h = HI ? (w >> 16) : w;
  f32x2 r; r.x = fp8_dec1(h & 0xFF); r.y = fp8_dec1((h >> 8) & 0xFF);
  return r;
}
#endif
#if __has_builtin(__builtin_amdgcn_cvt_pk_fp8_f32)
__device__ __forceinline__ unsigned char fp8_enc_byte(float a) {
  return (unsigned char)(__builtin_amdgcn_cvt_pk_fp8_f32(a, a, 0, false) & 0xFF);
}
#else
__device__ __forceinline__ unsigned fp8_enc1(float f) {
  unsigned s = (__float_as_uint(f) >> 31) << 7;
  float a = fabsf(f);
  if (a >= 448.f) return s | 0x7E;
  if (a < 0.015625f) {
    int m = (int)(a * 512.f + 0.5f);
    return s | (unsigned)(m > 7 ? 7 : m);
  }
  int ex; (void)frexpf(a, &ex);
  int E = ex - 1;
  float sig = a * exp2f((float)(-E));
  int m = (int)((sig - 1.f) * 8.f + 0.5f);
  if (m == 8) { m = 0; E += 1; }
  if (E > 8) return s | 0x7E;
  return s | (unsigned)((E + 7) << 3) | (unsigned)m;
}
__device__ __forceinline__ unsigned char fp8_enc_byte(float a) {
  return (unsigned char)fp8_enc1(a);
}
#endif

// ---------------------------------------------------------------------------
// Weight prep: wt[mat][c][k] = bf16(W[mat>>1][k][c]);  mat=(l*8+t)*2+which
// ---------------------------------------------------------------------------
__global__ __launch_bounds__(256) void prep_w(
    const float* __restrict__ Wl, const float* __restrict__ Wr,
    unsigned short* __restrict__ wt)
{
  int elem = blockIdx.x * 256 + threadIdx.x;
  int mat = elem >> 14;
  int c = (elem >> 7) & 127;
  int k = elem & 127;
  const float* srcb = (mat & 1) ? Wr : Wl;
  wt[elem] = f2b(srcb[((long)(mat >> 1) << 14) + (k << 7) + c]);
}

// ---------------------------------------------------------------------------
// Cast emb (f32) -> xb (bf16), all 3 types fused (float4 chunks).
// ---------------------------------------------------------------------------
__global__ __launch_bounds__(256) void cast_all(
    const float* __restrict__ e0, const float* __restrict__ e1,
    const float* __restrict__ e2, unsigned short* __restrict__ x0,
    unsigned short* __restrict__ x1, unsigned short* __restrict__ x2,
    int n0, int n1, int n2)
{
  int i = blockIdx.x * 256 + threadIdx.x;
  const float* s; unsigned short* d; int loc = i;
  if (loc < n0) { s = e0; d = x0; }
  else {
    loc -= n0;
    if (loc < n1) { s = e1; d = x1; }
    else { loc -= n1; if (loc >= n2) return; s = e2; d = x2; }
  }
  float4 v = *(const float4*)(s + (long)loc * 4);
  ushort4 o = {f2b(v.x), f2b(v.y), f2b(v.z), f2b(v.w)};
  *(ushort4*)(d + (long)loc * 4) = o;
}

// ---------------------------------------------------------------------------
// Precompute masked bias sums: bsum[l][ty][c] = sum_{t in mask(ty)} bias[l,t,c]
// ---------------------------------------------------------------------------
__global__ __launch_bounds__(128) void prep_bias(
    const float* __restrict__ bias, float* __restrict__ bsum)
{
  int c = threadIdx.x;
  const int TM[3] = {0x35, 0x42, 0x88};
  for (int l = 0; l < 2; ++l)
    for (int ty = 0; ty < 3; ++ty) {
      float s = 0.f;
      for (int t = 0; t < 8; ++t)
        if (TM[ty] & (1 << t)) s += bias[(l * 8 + t) * 128 + c];
      bsum[(l * 3 + ty) * 128 + c] = s;
    }
}

// ---------------------------------------------------------------------------
// Multi-weight MFMA projection: block stages one 128-row x-tile ONCE, then
// loops over up to 4 weight matrices. mode: 0 f32, 2 bf16, 3 fp8.
// ---------------------------------------------------------------------------
struct MPJob {
  const unsigned short* x; int N; int nw;
  const unsigned short* wt[4]; void* out[4]; int mode[4];
};
struct MPArgs { MPJob j[4]; int off[5]; };

__global__ __launch_bounds__(256) void mproj_multi(MPArgs a)
{
  __shared__ __align__(16) char lx[32768];
  __shared__ __align__(16) char lw[32768];
  int blk = blockIdx.x, t = 0;
  while (blk >= a.off[t + 1]) ++t;
  const MPJob& J = a.j[t];
  const long r0 = (long)(blk - a.off[t]) * 128;
  const int tid = threadIdx.x;
  const int N = J.N;

#pragma unroll
  for (int i = 0; i < 8; ++i) {
    int ch = i * 256 + tid;
    int row = ch >> 4, k0 = (ch & 15) << 3;
    uint4 xv = {0u, 0u, 0u, 0u};
    if (r0 + row < N) xv = *(const uint4*)(J.x + (r0 + row) * 128 + k0);
    *(uint4*)(lx + ((row * 256 + k0 * 2) ^ ((row & 7) << 4))) = xv;
  }

  const int lane = tid & 63;
  const int lr = lane & 15, lk = lane >> 4;
  const int rbase = (tid >> 6) * 32;

  for (int w = 0; w < J.nw; ++w) {
    __syncthreads();
    const unsigned short* wt = J.wt[w];
#pragma unroll
    for (int i = 0; i < 8; ++i) {
      int ch = i * 256 + tid;
      int row = ch >> 4;
      uint4 wv = *(const uint4*)(wt + (long)ch * 8);
      *(uint4*)(lw + ((ch * 16) ^ ((row & 7) << 4))) = wv;
    }
    __syncthreads();

    f32x4 acc[2][8] = {};
#pragma unroll
    for (int kb = 0; kb < 4; ++kb) {
      int k = kb * 32 + lk * 8;
      int ra = rbase + lr;
      bf16x8 a0 = *(const bf16x8*)(lx + ((ra * 256 + k * 2) ^ ((ra & 7) << 4)));
      int rb = rbase + 16 + lr;
      bf16x8 a1 = *(const bf16x8*)(lx + ((rb * 256 + k * 2) ^ ((rb & 7) << 4)));
#pragma unroll
      for (int cc = 0; cc < 8; ++cc) {
        int col = cc * 16 + lr;
        bf16x8 bfr = *(const bf16x8*)(lw + ((col * 256 + k * 2) ^ ((col & 7) << 4)));
        acc[0][cc] = __builtin_amdgcn_mfma_f32_16x16x32_bf16(a0, bfr, acc[0][cc], 0, 0, 0);
        acc[1][cc] = __builtin_amdgcn_mfma_f32_16x16x32_bf16(a1, bfr, acc[1][cc], 0, 0, 0);
      }
    }
    int mode = J.mode[w];
    void* outv = J.out[w];
#pragma unroll
    for (int rt = 0; rt < 2; ++rt) {
      int rowb = rbase + rt * 16 + lk * 4;
#pragma unroll
      for (int cc = 0; cc < 8; ++cc) {
        int col = cc * 16 + lr;
#pragma unroll
        for (int q = 0; q < 4; ++q) {
          long row = r0 + rowb + q;
          if (row < N) {
            if (mode == 3)
              ((unsigned char*)outv)[row * 128 + col] = fp8_enc_byte(acc[rt][cc][q]);
            else if (mode == 2)
              ((unsigned short*)outv)[row * 128 + col] = f2b(acc[rt][cc][q]);
            else
              ((float*)outv)[row * 128 + col] = acc[rt][cc][q];
          }
        }
      }
    }
  }
}

// ---------------------------------------------------------------------------
// Atomic-free bucketed CSR build (bucket = 128 dst nodes, 4096 edges/block).
// ---------------------------------------------------------------------------
struct BArgs {
  const int* src[5]; const int* dst[5];
  int* cnt[5];
  int* tmp[5];
  int* rs[5];
  int* csrc[5];
  int E[5], Nd[5], NB[5], B[5];
  int cOff[6], fOff[6];
};

__global__ __launch_bounds__(256) void bucket_count(BArgs a)
{
  __shared__ int h[512];
  int blk = blockIdx.x, t = 0;
  while (blk >= a.cOff[t + 1]) ++t;
  int lb = blk - a.cOff[t];
  int B = a.B[t], NB = a.NB[t], E = a.E[t];
  for (int i = threadIdx.x; i < B; i += 256) h[i] = 0;
  __syncthreads();
  const int* dst = a.dst[t];
  int base = lb * 4096;
#pragma unroll
  for (int j = 0; j < 16; ++j) {
    int e = base + j * 256 + threadIdx.x;
    if (e < E) atomicAdd(&h[dst[e] >> 7], 1);   // LDS atomic
  }
  __syncthreads();
  int* cnt = a.cnt[t];
  for (int b = threadIdx.x; b < B; b += 256) cnt[b * NB + lb] = h[b];
}

__global__ __launch_bounds__(1024) void bucket_scan(BArgs a)
{
  int t = blockIdx.x;
  int n = a.B[t] * a.NB[t];
  int* dp = a.cnt[t];
  __shared__ int wsum[16];
  __shared__ int sbase, ctot;
  int tid = threadIdx.x;
  int lane = tid & 63, wid = tid >> 6;
  if (tid == 0) sbase = 0;
  __syncthreads();
  for (int chunk = 0; chunk < n; chunk += 16384) {
    int idx0 = chunk + tid * 16;
    int v[16], lsum = 0;
#pragma unroll
    for (int j = 0; j < 16; ++j) {
      v[j] = (idx0 + j < n) ? dp[idx0 + j] : 0;
      lsum += v[j];
    }
    int sc = lsum;
#pragma unroll
    for (int o = 1; o < 64; o <<= 1) {
      int u = __shfl_up(sc, o);
      if (lane >= o) sc += u;
    }
    if (lane == 63) wsum[wid] = sc;
    __syncthreads();
    if (wid == 0) {
      int w = (lane < 16) ? wsum[lane] : 0;
      int s2 = w;
#pragma unroll
      for (int o = 1; o < 16; o <<= 1) {
        int u = __shfl_up(s2, o);
        if (lane >= o) s2 += u;
      }
      if (lane < 16) wsum[lane] = s2 - w;
      if (lane == 15) ctot = s2;
    }
    __syncthreads();
    int excl = sbase + wsum[wid] + (sc - lsum);
#pragma unroll
    for (int j = 0; j < 16; ++j) {
      if (idx0 + j < n) dp[idx0 + j] = excl;
      excl += v[j];
    }
    __syncthreads();
    if (tid == 0) sbase += ctot;
    __syncthreads();
  }
}

__global__ __launch_bounds__(256) void bucket_scatter(BArgs a)
{
  __shared__ int cur[512];
  int blk = blockIdx.x, t = 0;
  while (blk >= a.cOff[t + 1]) ++t;
  int lb = blk - a.cOff[t];
  int B = a.B[t], NB = a.NB[t], E = a.E[t];
  const int* cnt = a.cnt[t];
  for (int b = threadIdx.x; b < B; b += 256) cur[b] = cnt[b * NB + lb];
  __syncthreads();
  const int* src = a.src[t];
  const int* dst = a.dst[t];
  int* tmp = a.tmp[t];
  int base = lb * 4096;
#pragma unroll
  for (int j = 0; j < 16; ++j) {
    int e = base + j * 256 + threadIdx.x;
    if (e < E) {
      int dv = dst[e];
      int pos = atomicAdd(&cur[dv >> 7], 1);    // LDS atomic
      tmp[pos] = ((dv & 127) << 16) | src[e];
    }
  }
}

__global__ __launch_bounds__(256) void bucket_finalize(BArgs a)
{
  __shared__ int h[128], sc[128], ex[128], cur[128];
  int blk = blockIdx.x, t = 0;
  while (blk >= a.fOff[t + 1]) ++t;
  int b = blk - a.fOff[t];
  int B = a.B[t], NB = a.NB[t], E = a.E[t], Nd = a.Nd[t];
  const int* cnt = a.cnt[t];
  const int* tmp = a.tmp[t];
  int* rs = a.rs[t];
  int* csrc = a.csrc[t];
  int tid = threadIdx.x;
  int beg = cnt[b * NB];
  int end = (b + 1 < B) ? cnt[(b + 1) * NB] : E;
  if (tid < 128) h[tid] = 0;
  __syncthreads();
  for (int i = beg + tid; i < end; i += 256)
    atomicAdd(&h[tmp[i] >> 16], 1);             // LDS atomic
  __syncthreads();
  if (tid < 128) sc[tid] = h[tid];
  __syncthreads();
#pragma unroll
  for (int off = 1; off < 128; off <<= 1) {
    int v = (tid < 128 && tid >= off) ? sc[tid - off] : 0;
    __syncthreads();
    if (tid < 128) sc[tid] += v;
    __syncthreads();
  }
  if (tid < 128) {
    ex[tid] = sc[tid] - h[tid];
    cur[tid] = 0;
    int dg = b * 128 + tid;
    if (dg < Nd) rs[dg] = beg + ex[tid];
  }
  if (b == B - 1 && tid == 0) rs[Nd] = E;
  __syncthreads();
  for (int i = beg + tid; i < end; i += 256) {
    int v = tmp[i];
    int d = v >> 16;
    int r = atomicAdd(&cur[d], 1);              // LDS atomic
    csrc[beg + ex[d] + r] = v & 0xFFFF;
  }
}

// ---------------------------------------------------------------------------
// Fused gather + LayerNorm. Two shapes:
//  fast==0 (gene/mirna): 1 row/wave, 16 lanes/edge, 4 quarter-streams.
//  fast==1 (cpg, low degree): 4 rows/wave (16-lane groups), serial edges,
//    no butterfly, epilogue fully lane-parallel — amortizes per-row cost.
// hs fp8 (128B rows), hd bf16.
// ---------------------------------------------------------------------------
struct GSeg {
  const int* rs[3]; const int* csrc[3];
  const unsigned char* hs[3]; const unsigned short* hd[3];
  const float* att[3];
  const float* aggSelf;
  const float* xin;
  float* xf; unsigned short* xb;
  const float* bsum;
  const float* gam; const float* bet;
  int Nd; int ntypes; int fast;
};
struct GArgs { GSeg s[3]; int off[4]; };

#define GA_EDGE(U)                                                          \
    {                                                                       \
      f32x2 h0 = fp8x2_dec<false>((U).x), h1 = fp8x2_dec<true>((U).x);      \
      f32x2 h2 = fp8x2_dec<false>((U).y), h3 = fp8x2_dec<true>((U).y);      \
      f32x2 v0 = h0 + H0, v1 = h1 + H1, v2 = h2 + H2, v3 = h3 + H3;         \
      v0 = pk_max(v0, v0 * 0.2f);                                           \
      v1 = pk_max(v1, v1 * 0.2f);                                           \
      v2 = pk_max(v2, v2 * 0.2f);                                           \
      v3 = pk_max(v3, v3 * 0.2f);                                           \
      f32x2 pv = pk_fma(v0, A0, pk_fma(v1, A1, pk_fma(v2, A2, v3 * A3)));   \
      float p = pv.x + pv.y;                                                \
      p += __shfl_xor(p, 1);                                                \
      float a = __expf(fminf(p, 60.f));                                     \
      f32x2 av = {a, a};                                                    \
      n0 = pk_fma(h0, av, n0);                                              \
      n1 = pk_fma(h1, av, n1);                                              \
      n2 = pk_fma(h2, av, n2);                                              \
      n3 = pk_fma(h3, av, n3);                                              \
      D += a;                                                               \
    }

__global__ __launch_bounds__(256) void gat_gather_ln(GArgs g)
{
  int blk = blockIdx.x, si = 0;
  while (blk >= g.off[si + 1]) ++si;
  const GSeg& sg = g.s[si];
  int lane = threadIdx.x & 63;

  if (sg.fast) {
    int wv = threadIdx.x >> 6;
    int grp = lane >> 4, j = lane & 15;
    int d = (blk - g.off[si]) * 16 + wv * 4 + grp;
    bool act = d < sg.Nd;
    const float* ap = sg.att[0] + 8 * j;
    float4 aa = *(const float4*)ap;
    float4 ab = *(const float4*)(ap + 4);
    f32x2 A0 = {aa.x, aa.y}, A1 = {aa.z, aa.w};
    f32x2 A2 = {ab.x, ab.y}, A3 = {ab.z, ab.w};
    f32x2 H0 = {0.f, 0.f}, H1 = {0.f, 0.f}, H2 = {0.f, 0.f}, H3 = {0.f, 0.f};
    int beg = 0, end = 0;
    if (act) {
      uint4 hu = *((const uint4*)(sg.hd[0] + (long)d * 128) + j);
      H0 = bf2x2(hu.x); H1 = bf2x2(hu.y);
      H2 = bf2x2(hu.z); H3 = bf2x2(hu.w);
      beg = sg.rs[0][d];
      end = sg.rs[0][d + 1];
    }
    const int* cs = sg.csrc[0];
    const unsigned char* hsk = sg.hs[0];
    f32x2 n0 = {0.f, 0.f}, n1 = {0.f, 0.f}, n2 = {0.f, 0.f}, n3 = {0.f, 0.f};
    float D = 0.f;
    int i = beg;
    int sA = (i < end) ? cs[i] : 0;
    int sB = (i + 1 < end) ? cs[i + 1] : 0;
    for (; i + 1 < end; i += 2) {
      uint2 u0 = *((const uint2*)(hsk + (long)sA * 128) + j);
      uint2 u1 = *((const uint2*)(hsk + (long)sB * 128) + j);
      sA = (i + 2 < end) ? cs[i + 2] : 0;
      sB = (i + 3 < end) ? cs[i + 3] : 0;
      GA_EDGE(u0);
      GA_EDGE(u1);
    }
    if (i < end) {
      uint2 u = *((const uint2*)(hsk + (long)sA * 128) + j);
      GA_EDGE(u);
    }
    float inv = 1.f / (D + 1e-16f);
    f32x2 iv = {inv, inv};
    f32x2 T0 = n0 * iv, T1 = n1 * iv, T2 = n2 * iv, T3 = n3 * iv;

    long base = (long)d * 128 + 8 * j;
    float v[8] = {T0.x, T0.y, T1.x, T1.y, T2.x, T2.y, T3.x, T3.y};
    if (act) {
      float4 sA0 = *(const float4*)(sg.aggSelf + base);
      float4 sA1 = *(const float4*)(sg.aggSelf + base + 4);
      float4 bb0 = *(const float4*)(sg.bsum + 8 * j);
      float4 bb1 = *(const float4*)(sg.bsum + 8 * j + 4);
      v[0] += sA0.x + bb0.x; v[1] += sA0.y + bb0.y;
      v[2] += sA0.z + bb0.z; v[3] += sA0.w + bb0.w;
      v[4] += sA1.x + bb1.x; v[5] += sA1.y + bb1.y;
      v[6] += sA1.z + bb1.z; v[7] += sA1.w + bb1.w;
    }
#pragma unroll
    for (int c = 0; c < 8; ++c) v[c] = v[c] > 0.f ? v[c] : __expf(v[c]) - 1.f;
    float xr[8] = {v[0], v[1], v[2], v[3], v[4], v[5], v[6], v[7]};
    if (act) {
      float4 xi0 = *(const float4*)(sg.xin + base);
      float4 xi1 = *(const float4*)(sg.xin + base + 4);
      xr[0] += xi0.x; xr[1] += xi0.y; xr[2] += xi0.z; xr[3] += xi0.w;
      xr[4] += xi1.x; xr[5] += xi1.y; xr[6] += xi1.z; xr[7] += xi1.w;
    }
    float ssum = ((xr[0] + xr[1]) + (xr[2] + xr[3])) +
                 ((xr[4] + xr[5]) + (xr[6] + xr[7]));
#pragma unroll
    for (int o = 1; o < 16; o <<= 1) ssum += __shfl_xor(ssum, o);
    float mu = ssum * 0.0078125f;
    float qs = 0.f;
#pragma unroll
    for (int c = 0; c < 8; ++c) { float dd = xr[c] - mu; qs += dd * dd; }
#pragma unroll
    for (int o = 1; o < 16; o <<= 1) qs += __shfl_xor(qs, o);
    float rr = rsqrtf(qs * 0.0078125f + 1e-5f);
    if (act) {
      float4 g0 = *(const float4*)(sg.gam + 8 * j);
      float4 g1 = *(const float4*)(sg.gam + 8 * j + 4);
      float4 e0 = *(const float4*)(sg.bet + 8 * j);
      float4 e1 = *(const float4*)(sg.bet + 8 * j + 4);
      float y[8];
      y[0] = (xr[0] - mu) * rr * g0.x + e0.x;
      y[1] = (xr[1] - mu) * rr * g0.y + e0.y;
      y[2] = (xr[2] - mu) * rr * g0.z + e0.z;
      y[3] = (xr[3] - mu) * rr * g0.w + e0.w;
      y[4] = (xr[4] - mu) * rr * g1.x + e1.x;
      y[5] = (xr[5] - mu) * rr * g1.y + e1.y;
      y[6] = (xr[6] - mu) * rr * g1.z + e1.z;
      y[7] = (xr[7] - mu) * rr * g1.w + e1.w;
      float4 o0 = {y[0], y[1], y[2], y[3]};
      float4 o1 = {y[4], y[5], y[6], y[7]};
      *(float4*)(sg.xf + base) = o0;
      *(float4*)(sg.xf + base + 4) = o1;
      uint4 ub;
      ub.x = (unsigned)f2b(y[0]) | ((unsigned)f2b(y[1]) << 16);
      ub.y = (unsigned)f2b(y[2]) | ((unsigned)f2b(y[3]) << 16);
      ub.z = (unsigned)f2b(y[4]) | ((unsigned)f2b(y[5]) << 16);
      ub.w = (unsigned)f2b(y[6]) | ((unsigned)f2b(y[7]) << 16);
      *(uint4*)(sg.xb + base) = ub;
    }
    return;
  }

  // ---- standard path: 1 row/wave, 4 quarter-streams ----
  int d = (blk - g.off[si]) * 4 + (threadIdx.x >> 6);
  if (d >= sg.Nd) return;
  int q = lane >> 4, j = lane & 15;
  f32x2 T0 = {0.f, 0.f}, T1 = {0.f, 0.f}, T2 = {0.f, 0.f}, T3 = {0.f, 0.f};
  for (int k = 0; k < sg.ntypes; ++k) {
    const float* ap = sg.att[k] + 8 * j;
    float4 aa = *(const float4*)ap;
    float4 ab = *(const float4*)(ap + 4);
    f32x2 A0 = {aa.x, aa.y}, A1 = {aa.z, aa.w};
    f32x2 A2 = {ab.x, ab.y}, A3 = {ab.z, ab.w};
    uint4 hu = *((const uint4*)(sg.hd[k] + (long)d * 128) + j);
    f32x2 H0 = bf2x2(hu.x), H1 = bf2x2(hu.y);
    f32x2 H2 = bf2x2(hu.z), H3 = bf2x2(hu.w);
    const int* cs = sg.csrc[k];
    const unsigned char* hsk = sg.hs[k];
    int beg = sg.rs[k][d], end = sg.rs[k][d + 1];
    f32x2 n0 = {0.f, 0.f}, n1 = {0.f, 0.f}, n2 = {0.f, 0.f}, n3 = {0.f, 0.f};
    float D = 0.f;
    int i = beg + q;
    int sA = (i < end) ? cs[i] : 0;
    int sB = (i + 4 < end) ? cs[i + 4] : 0;
    for (; i + 4 < end; i += 8) {
      uint2 u0 = *((const uint2*)(hsk + (long)sA * 128) + j);
      uint2 u1 = *((const uint2*)(hsk + (long)sB * 128) + j);
      sA = (i + 8 < end) ? cs[i + 8] : 0;
      sB = (i + 12 < end) ? cs[i + 12] : 0;
      GA_EDGE(u0);
      GA_EDGE(u1);
    }
    if (i < end) {
      uint2 u = *((const uint2*)(hsk + (long)sA * 128) + j);
      GA_EDGE(u);
    }
#pragma unroll
    for (int o = 16; o < 64; o <<= 1) {
      n0.x += __shfl_xor(n0.x, o); n0.y += __shfl_xor(n0.y, o);
      n1.x += __shfl_xor(n1.x, o); n1.y += __shfl_xor(n1.y, o);
      n2.x += __shfl_xor(n2.x, o); n2.y += __shfl_xor(n2.y, o);
      n3.x += __shfl_xor(n3.x, o); n3.y += __shfl_xor(n3.y, o);
      D += __shfl_xor(D, o);
    }
    float inv = 1.f / (D + 1e-16f);
    f32x2 iv = {inv, inv};
    T0 = pk_fma(n0, iv, T0);
    T1 = pk_fma(n1, iv, T1);
    T2 = pk_fma(n2, iv, T2);
    T3 = pk_fma(n3, iv, T3);
  }

  long base = (long)d * 128 + 8 * j;
  float4 sA0 = *(const float4*)(sg.aggSelf + base);
  float4 sA1 = *(const float4*)(sg.aggSelf + base + 4);
  float4 bb0 = *(const float4*)(sg.bsum + 8 * j);
  float4 bb1 = *(const float4*)(sg.bsum + 8 * j + 4);
  float v[8];
  v[0] = sA0.x + T0.x + bb0.x; v[1] = sA0.y + T0.y + bb0.y;
  v[2] = sA0.z + T1.x + bb0.z; v[3] = sA0.w + T1.y + bb0.w;
  v[4] = sA1.x + T2.x + bb1.x; v[5] = sA1.y + T2.y + bb1.y;
  v[6] = sA1.z + T3.x + bb1.z; v[7] = sA1.w + T3.y + bb1.w;
#pragma unroll
  for (int c = 0; c < 8; ++c) v[c] = v[c] > 0.f ? v[c] : __expf(v[c]) - 1.f;
  float4 xi0 = *(const float4*)(sg.xin + base);
  float4 xi1 = *(const float4*)(sg.xin + base + 4);
  float xr[8] = {xi0.x + v[0], xi0.y + v[1], xi0.z + v[2], xi0.w + v[3],
                 xi1.x + v[4], xi1.y + v[5], xi1.z + v[6], xi1.w + v[7]};
  float ssum = ((xr[0] + xr[1]) + (xr[2] + xr[3])) +
               ((xr[4] + xr[5]) + (xr[6] + xr[7]));
#pragma unroll
  for (int o = 1; o < 16; o <<= 1) ssum += __shfl_xor(ssum, o);
  float mu = ssum * 0.0078125f;
  float qs = 0.f;
#pragma unroll
  for (int c = 0; c < 8; ++c) { float dd = xr[c] - mu; qs += dd * dd; }
#pragma unroll
  for (int o = 1; o < 16; o <<= 1) qs += __shfl_xor(qs, o);
  float rr = rsqrtf(qs * 0.0078125f + 1e-5f);
  float4 g0 = *(const float4*)(sg.gam + 8 * j);
  float4 g1 = *(const float4*)(sg.gam + 8 * j + 4);
  float4 e0 = *(const float4*)(sg.bet + 8 * j);
  float4 e1 = *(const float4*)(sg.bet + 8 * j + 4);
  float y[8];
  y[0] = (xr[0] - mu) * rr * g0.x + e0.x;
  y[1] = (xr[1] - mu) * rr * g0.y + e0.y;
  y[2] = (xr[2] - mu) * rr * g0.z + e0.z;
  y[3] = (xr[3] - mu) * rr * g0.w + e0.w;
  y[4] = (xr[4] - mu) * rr * g1.x + e1.x;
  y[5] = (xr[5] - mu) * rr * g1.y + e1.y;
  y[6] = (xr[6] - mu) * rr * g1.z + e1.z;
  y[7] = (xr[7] - mu) * rr * g1.w + e1.w;
  if (q == 0) {
    float4 o0 = {y[0], y[1], y[2], y[3]};
    float4 o1 = {y[4], y[5], y[6], y[7]};
    *(float4*)(sg.xf + base) = o0;
    *(float4*)(sg.xf + base + 4) = o1;
    uint4 ub;
    ub.x = (unsigned)f2b(y[0]) | ((unsigned)f2b(y[1]) << 16);
    ub.y = (unsigned)f2b(y[2]) | ((unsigned)f2b(y[3]) << 16);
    ub.z = (unsigned)f2b(y[4]) | ((unsigned)f2b(y[5]) << 16);
    ub.w = (unsigned)f2b(y[6]) | ((unsigned)f2b(y[7]) << 16);
    *(uint4*)(sg.xb + base) = ub;
  }
}
#undef GA_EDGE

// ---------------------------------------------------------------------------
// zgemm stage 1: TWO 64-row chunks per block (halves partial traffic).
// ---------------------------------------------------------------------------
struct ZArgs {
  const float* batch[3]; const float* x[3]; float* zp[3]; int N[3];
  int off[4];
};

__global__ __launch_bounds__(256) void zgemm_all(ZArgs z)
{
  __shared__ __align__(16) float xl[64 * 128];
  __shared__ __align__(16) float bl[64 * 65];
  int blk = blockIdx.x, s = 0;
  while (blk >= z.off[s + 1]) ++s;
  int c = blk - z.off[s];
  const float* batch = z.batch[s];
  const float* x = z.x[s];
  int N = z.N[s];
  int tid = threadIdx.x;
  int cg = (tid & 31) * 4;
  int bg = (tid >> 5) * 8;
  float acc[8][4] = {};
#pragma unroll
  for (int cc = 0; cc < 2; ++cc) {
    int n0 = (c * 2 + cc) * 64;
    if (n0 >= N) break;
    __syncthreads();
    for (int i = tid; i < 64 * 128; i += 256) {
      int nn = i >> 7;
      xl[i] = (n0 + nn < N) ? x[(long)(n0 + nn) * 128 + (i & 127)] : 0.f;
    }
    for (int i = tid; i < 64 * 64; i += 256) {
      int b = i >> 6, nn = i & 63;
      bl[nn * 65 + b] = (n0 + nn < N) ? batch[(long)b * N + n0 + nn] : 0.f;
    }
    __syncthreads();
    for (int nn = 0; nn < 64; ++nn) {
      float4 xv = *(const float4*)(xl + nn * 128 + cg);
#pragma unroll
      for (int i = 0; i < 8; ++i) {
        float bv = bl[nn * 65 + bg + i];
        acc[i][0] = fmaf(bv, xv.x, acc[i][0]);
        acc[i][1] = fmaf(bv, xv.y, acc[i][1]);
        acc[i][2] = fmaf(bv, xv.z, acc[i][2]);
        acc[i][3] = fmaf(bv, xv.w, acc[i][3]);
      }
    }
  }
  float* zp = z.zp[s] + (long)c * 8192;
#pragma unroll
  for (int i = 0; i < 8; ++i) {
    float4 v = {acc[i][0], acc[i][1], acc[i][2], acc[i][3]};
    *(float4*)(zp + (bg + i) * 128 + cg) = v;
  }
}

// ---------------------------------------------------------------------------
// zfinal: partial reduce (8 dual accumulators) + scale + LayerNorm -> out.
// ---------------------------------------------------------------------------
__global__ __launch_bounds__(256) void zfinal(
    const float* __restrict__ zp0, const float* __restrict__ zp1,
    const float* __restrict__ zp2, int G0, int G1, int G2,
    float s0, float s1, float s2, const float* __restrict__ gam,
    const float* __restrict__ bet, float* __restrict__ out)
{
  int blk = blockIdx.x;
  int ty = blk >> 4;
  int rowL = (blk & 15) * 4 + (threadIdx.x >> 6);
  int lane = threadIdx.x & 63;
  const float* zp = ty == 0 ? zp0 : (ty == 1 ? zp1 : zp2);
  int G = ty == 0 ? G0 : (ty == 1 ? G1 : G2);
  float sc = ty == 0 ? s0 : (ty == 1 ? s1 : s2);
  long i0 = rowL * 128 + lane, i1 = i0 + 64;
  float a0[8], a1[8];
#pragma unroll
  for (int u = 0; u < 8; ++u) { a0[u] = 0.f; a1[u] = 0.f; }
  int g = 0;
  for (; g + 8 <= G; g += 8) {
#pragma unroll
    for (int u = 0; u < 8; ++u) {
      a0[u] += zp[(long)(g + u) * 8192 + i0];
      a1[u] += zp[(long)(g + u) * 8192 + i1];
    }
  }
  for (; g < G; ++g) { a0[0] += zp[(long)g * 8192 + i0]; a1[0] += zp[(long)g * 8192 + i1]; }
  float x0 = (((a0[0] + a0[1]) + (a0[2] + a0[3])) + ((a0[4] + a0[5]) + (a0[6] + a0[7]))) * sc;
  float x1 = (((a1[0] + a1[1]) + (a1[2] + a1[3])) + ((a1[4] + a1[5]) + (a1[6] + a1[7]))) * sc;
  float s = x0 + x1;
#pragma unroll
  for (int o = 32; o > 0; o >>= 1) s += __shfl_xor(s, o);
  float mu = s * 0.0078125f;
  float d0 = x0 - mu, d1 = x1 - mu;
  float qv = d0 * d0 + d1 * d1;
#pragma unroll
  for (int o = 32; o > 0; o >>= 1) qv += __shfl_xor(qv, o);
  float r = rsqrtf(qv * 0.0078125f + 1e-5f);
  long base = (long)(ty * 64 + rowL) * 128;
  out[base + lane]      = d0 * r * gam[ty * 128 + lane]      + bet[ty * 128 + lane];
  out[base + 64 + lane] = d1 * r * gam[ty * 128 + 64 + lane] + bet[ty * 128 + 64 + lane];
}

// ---------------------------------------------------------------------------
extern "C" void kernel_launch(void* const* d_in, const int* in_sizes, int n_in,
                              void* d_out, int out_size, void* d_ws, size_t ws_size,
                              hipStream_t stream)
{
  const float* batchp[3] = {(const float*)d_in[0], (const float*)d_in[1],
                            (const float*)d_in[2]};
  const float* emb[3] = {(const float*)d_in[3], (const float*)d_in[4],
                         (const float*)d_in[5]};
  const float* Wl   = (const float*)d_in[6];
  const float* Wr   = (const float*)d_in[7];
  const float* att  = (const float*)d_in[8];
  const float* bias = (const float*)d_in[9];
  const float* lng  = (const float*)d_in[10];
  const float* lnb  = (const float*)d_in[11];
  const float* outg = (const float*)d_in[12];
  const float* outb = (const float*)d_in[13];
  const int* eiP[8]; int E[8];
  for (int t = 0; t < 8; ++t) { eiP[t] = (const int*)d_in[14 + t]; E[t] = in_sizes[14 + t] / 2; }
  int Nn[3] = {in_sizes[3] / 128, in_sizes[4] / 128, in_sizes[5] / 128};
  long Ntot = (long)Nn[0] + Nn[1] + Nn[2];

  const int SI[5] = {1, 0, 2, 0, 0};
  const int DI[5] = {0, 1, 0, 2, 0};

  char* p = (char*)d_ws;
  auto carve = [&](size_t b) -> void* {
    void* r = (void*)p; p += (b + 255) & ~(size_t)255; return r;
  };
  float* xf[3];
  for (int ty = 0; ty < 3; ++ty) xf[ty] = (float*)carve((size_t)Nn[ty] * 128 * 4);
  unsigned short* xb[3];
  for (int ty = 0; ty < 3; ++ty) xb[ty] = (unsigned short*)carve((size_t)Nn[ty] * 128 * 2);
  float* aggAll = (float*)carve((size_t)Ntot * 128 * 4);
  float* agg[3] = {aggAll, aggAll + (long)Nn[0] * 128, aggAll + ((long)Nn[0] + Nn[1]) * 128};
  unsigned short* hdT[5];
  for (int t = 0; t < 5; ++t) hdT[t] = (unsigned short*)carve((size_t)Nn[DI[t]] * 128 * 2);
  long hsElems = 0;
  for (int t = 0; t < 5; ++t) hsElems += (long)Nn[SI[t]] * 128;
  unsigned char* hs8base = (unsigned char*)carve((size_t)hsElems);
  unsigned char* hs8T[5];
  {
    unsigned char* q8 = hs8base;
    for (int t = 0; t < 5; ++t) { hs8T[t] = q8; q8 += (long)Nn[SI[t]] * 128; }
  }
  float* bsumBuf = (float*)carve(2 * 3 * 128 * 4);
  unsigned short* wtb = (unsigned short*)carve((size_t)32 * 16384 * 2);

  int nch[3], nch2[3];
  for (int ty = 0; ty < 3; ++ty) {
    nch[ty] = (Nn[ty] + 63) / 64;
    nch2[ty] = (nch[ty] + 1) / 2;
  }
  float* zpBase = (float*)carve((size_t)(nch2[0] + nch2[1] + nch2[2]) * 8192 * 4);
  float* zp[3];
  zp[0] = zpBase;
  zp[1] = zp[0] + (long)nch2[0] * 8192;
  zp[2] = zp[1] + (long)nch2[1] * 8192;

  BArgs ba;
  {
    int cOff = 0, fOff = 0;
    for (int t = 0; t < 5; ++t) {
      int nd = Nn[DI[t]];
      ba.src[t] = eiP[t];
      ba.dst[t] = eiP[t] + E[t];
      ba.E[t] = E[t];
      ba.Nd[t] = nd;
      ba.NB[t] = (E[t] + 4095) / 4096;
      ba.B[t] = (nd + 127) / 128;
      ba.cnt[t] = (int*)carve((size_t)ba.B[t] * ba.NB[t] * 4);
      ba.tmp[t] = (int*)carve((size_t)E[t] * 4);
      ba.rs[t] = (int*)carve((size_t)(nd + 1) * 4);
      ba.csrc[t] = (int*)carve((size_t)E[t] * 4);
      ba.cOff[t] = cOff; cOff += ba.NB[t];
      ba.fOff[t] = fOff; fOff += ba.B[t];
    }
    ba.cOff[5] = cOff;
    ba.fOff[5] = fOff;
  }
  if ((size_t)(p - (char*)d_ws) > ws_size) return;

  auto WTB = [&](int l, int t, int which) {
    return wtb + ((long)((l * 8 + t) * 2 + which) << 14);
  };

  prep_w<<<2048, 256, 0, stream>>>(Wl, Wr, wtb);
  {
    int n0 = Nn[0] * 32, n1 = Nn[1] * 32, n2 = Nn[2] * 32;
    cast_all<<<(int)((n0 + n1 + n2 + 255) / 256), 256, 0, stream>>>(
        emb[0], emb[1], emb[2], xb[0], xb[1], xb[2], n0, n1, n2);
  }
  prep_bias<<<1, 128, 0, stream>>>(bias, bsumBuf);

  bucket_count<<<ba.cOff[5], 256, 0, stream>>>(ba);
  bucket_scan<<<5, 1024, 0, stream>>>(ba);
  bucket_scatter<<<ba.cOff[5], 256, 0, stream>>>(ba);
  bucket_finalize<<<ba.fOff[5], 256, 0, stream>>>(ba);

  const int GT[3][3] = {{0, 2, 4}, {1, -1, -1}, {3, -1, -1}};
  const int GN[3] = {3, 1, 1};

  for (int l = 0; l < 2; ++l) {
    const float* xinf[3] = {l == 0 ? emb[0] : xf[0],
                            l == 0 ? emb[1] : xf[1],
                            l == 0 ? emb[2] : xf[2]};
    // A) all 13 projections, multi-weight fused
    MPArgs mp;
    {
      int off = 0, nj = 0;
      auto addJob = [&](const unsigned short* x, int N) {
        mp.j[nj].x = x; mp.j[nj].N = N; mp.j[nj].nw = 0;
        mp.off[nj] = off; off += (N + 127) / 128;
        return nj++;
      };
      auto addW = [&](int ji, const unsigned short* wt, void* out, int mode) {
        MPJob& J = mp.j[ji];
        J.wt[J.nw] = wt; J.out[J.nw] = out; J.mode[J.nw] = mode; J.nw++;
      };
      int ga_ = addJob(xb[0], Nn[0]);
      addW(ga_, WTB(l, 1, 0), hs8T[1], 3);
      addW(ga_, WTB(l, 3, 0), hs8T[3], 3);
      addW(ga_, WTB(l, 4, 0), hs8T[4], 3);
      addW(ga_, WTB(l, 0, 1), hdT[0], 2);
      int gb_ = addJob(xb[0], Nn[0]);
      addW(gb_, WTB(l, 2, 1), hdT[2], 2);
      addW(gb_, WTB(l, 4, 1), hdT[4], 2);
      addW(gb_, WTB(l, 5, 0), agg[0], 0);
      int cj_ = addJob(xb[1], Nn[1]);
      addW(cj_, WTB(l, 0, 0), hs8T[0], 3);
      addW(cj_, WTB(l, 1, 1), hdT[1], 2);
      addW(cj_, WTB(l, 6, 0), agg[1], 0);
      int mj_ = addJob(xb[2], Nn[2]);
      addW(mj_, WTB(l, 2, 0), hs8T[2], 3);
      addW(mj_, WTB(l, 3, 1), hdT[3], 2);
      addW(mj_, WTB(l, 7, 0), agg[2], 0);
      mp.off[4] = off;
      mproj_multi<<<off, 256, 0, stream>>>(mp);
    }
    // B) fused gather + LN (cpg uses fast 4-rows-per-wave path)
    GArgs ga;
    {
      int off = 0;
      for (int s = 0; s < 3; ++s) {
        GSeg& sg = ga.s[s];
        sg.aggSelf = agg[s];
        sg.xin = xinf[s];
        sg.xf = xf[s];
        sg.xb = xb[s];
        sg.bsum = bsumBuf + (long)(l * 3 + s) * 128;
        sg.gam = lng + (long)(l * 3 + s) * 128;
        sg.bet = lnb + (long)(l * 3 + s) * 128;
        sg.Nd = Nn[s];
        sg.ntypes = GN[s];
        sg.fast = (s == 1) ? 1 : 0;
        for (int k = 0; k < GN[s]; ++k) {
          int t = GT[s][k];
          sg.rs[k] = ba.rs[t];
          sg.csrc[k] = ba.csrc[t];
          sg.hs[k] = hs8T[t];
          sg.hd[k] = hdT[t];
          sg.att[k] = att + (long)(l * 8 + t) * 128;
        }
        ga.off[s] = off;
        off += sg.fast ? (Nn[s] + 15) / 16 : (Nn[s] + 3) / 4;
      }
      ga.off[3] = off;
      gat_gather_ln<<<off, 256, 0, stream>>>(ga);
    }
  }

  ZArgs za;
  {
    int off = 0;
    for (int ty = 0; ty < 3; ++ty) {
      za.batch[ty] = batchp[ty];
      za.x[ty] = xf[ty];
      za.zp[ty] = zp[ty];
      za.N[ty] = Nn[ty];
      za.off[ty] = off;
      off += nch2[ty];
    }
    za.off[3] = off;
    zgemm_all<<<off, 256, 0, stream>>>(za);
  }
  zfinal<<<48, 256, 0, stream>>>(
      zp[0], zp[1], zp[2], nch2[0], nch2[1], nch2[2],
      (float)(1.0 / sqrt((double)Nn[0])), (float)(1.0 / sqrt((double)Nn[1])),
      (float)(1.0 / sqrt((double)Nn[2])), outg, outb, (float*)d_out);
}